// Round 4
// baseline (128.429 us; speedup 1.0000x reference)
//
#include <hip/hip_runtime.h>

#define NN    1024
#define INF   21
#define EE    128
#define NB    65   // 2*BINS+1
#define BINSV 32
#define TI    32
#define TJ    32

typedef float f32x4 __attribute__((ext_vector_type(4)));

// One kernel, one dispatch. Block = 32x32 output tile. Phase 1 recomputes
// a-rows, b-rows and ptab into LDS (total in-block FLOP is trivial); phase 2
// streams the 512 KB tile with nontemporal stores, reading only LDS.
__global__ __launch_bounds__(512, 4) void fused_kernel(
    const float* __restrict__ tf, const int* __restrict__ ri,
    const float* __restrict__ Wa, const float* __restrict__ ba,
    const float* __restrict__ Wb, const float* __restrict__ bb,
    const float* __restrict__ Wp, const float* __restrict__ bp,
    float* __restrict__ out) {
  __shared__ float a_lds[TI][EE];     // 16 KB
  __shared__ float b_lds[TJ][EE];     // 16 KB
  __shared__ float p_lds[NB][EE];     // 32.5 KB
  __shared__ float stf_i[TI][INF];
  __shared__ float stf_j[TJ][INF];
  __shared__ int   sri_i[TI];
  __shared__ int   sri_j[TJ];

  const int tid = threadIdx.x;
  const int i0 = blockIdx.y * TI;
  const int j0 = blockIdx.x * TJ;

  // ---- Phase 0: stage residue_index and target_feat rows ----
  if (tid < TI) sri_i[tid] = ri[i0 + tid];
  else if (tid >= 64 && tid < 64 + TJ) sri_j[tid - 64] = ri[j0 + tid - 64];
  for (int t = tid; t < TI * INF; t += 512)
    stf_i[t / INF][t % INF] = tf[(i0 + t / INF) * INF + (t % INF)];
  for (int t = tid; t < TJ * INF; t += 512)
    stf_j[t / INF][t % INF] = tf[(j0 + t / INF) * INF + (t % INF)];
  __syncthreads();

  // ---- Phase 1: a, b, ptab into LDS ----
  {
    const int e  = tid & 127;   // output feature
    const int r0 = tid >> 7;    // 0..3
    float wa[INF], wb[INF];
#pragma unroll
    for (int k = 0; k < INF; ++k) {
      wa[k] = Wa[e * INF + k];
      wb[k] = Wb[e * INF + k];
    }
    const float bav = ba[e], bbv = bb[e];
    for (int r = r0; r < TI; r += 4) {
      float s = bav;
#pragma unroll
      for (int k = 0; k < INF; ++k) s = fmaf(stf_i[r][k], wa[k], s);
      a_lds[r][e] = s;
    }
    for (int r = r0; r < TJ; r += 4) {
      float s = bbv;
#pragma unroll
      for (int k = 0; k < INF; ++k) s = fmaf(stf_j[r][k], wb[k], s);
      b_lds[r][e] = s;
    }
    const float bpv = bp[e];
    for (int d = r0; d < NB; d += 4)
      p_lds[d][e] = Wp[e * NB + d] + bpv;
  }
  __syncthreads();

  // ---- Phase 2: stream the tile. Wave = 2 j x 32 e4 -> 1 KB contiguous. ----
  const int e4 = tid & 31;   // f32x4 index within E
  const int jg = tid >> 5;   // 0..15
  const f32x4* __restrict__ a4 = reinterpret_cast<const f32x4*>(&a_lds[0][0]);
  const f32x4* __restrict__ b4 = reinterpret_cast<const f32x4*>(&b_lds[0][0]);
  const f32x4* __restrict__ p4 = reinterpret_cast<const f32x4*>(&p_lds[0][0]);

  for (int i = 0; i < TI; ++i) {
    const f32x4 av = a4[i * 32 + e4];
    const int rii = sri_i[i];
    f32x4* orow = reinterpret_cast<f32x4*>(
        out + ((size_t)(i0 + i) * NN + j0) * EE);
#pragma unroll
    for (int jp = 0; jp < 2; ++jp) {
      const int j = jp * 16 + jg;
      int d = rii - sri_j[j];
      d = min(max(d, -BINSV), BINSV) + BINSV;
      const f32x4 o = av + b4[j * 32 + e4] + p4[d * 32 + e4];
      __builtin_nontemporal_store(o, orow + j * 32 + e4);
    }
  }
}

extern "C" void kernel_launch(void* const* d_in, const int* in_sizes, int n_in,
                              void* d_out, int out_size, void* d_ws, size_t ws_size,
                              hipStream_t stream) {
  const float* tf = (const float*)d_in[0];
  const int*   ri = (const int*)d_in[1];
  const float* Wa = (const float*)d_in[2];
  const float* ba = (const float*)d_in[3];
  const float* Wb = (const float*)d_in[4];
  const float* bb = (const float*)d_in[5];
  const float* Wp = (const float*)d_in[6];
  const float* bp = (const float*)d_in[7];
  float* out = (float*)d_out;

  dim3 grid(NN / TJ, NN / TI);
  fused_kernel<<<grid, 512, 0, stream>>>(tf, ri, Wa, ba, Wb, bb, Wp, bp, out);
}

// Round 5
// 113.130 us; speedup vs baseline: 1.1352x; 1.1352x over previous
//
#include <hip/hip_runtime.h>

#define NN    1024
#define INF   21
#define EE    128
#define NB    65   // 2*BINS+1
#define BINSV 32

typedef float f32x4 __attribute__((ext_vector_type(4)));

// Kernel 1 (merged prep): blocks [0, NN) do the two linear projections;
// blocks [NN, NN+NB) build ptab[d][e] = Wp[e][d] + bp[e].
__global__ __launch_bounds__(128) void prep_kernel(
    const float* __restrict__ tf,
    const float* __restrict__ Wa, const float* __restrict__ ba,
    const float* __restrict__ Wb, const float* __restrict__ bb,
    const float* __restrict__ Wp, const float* __restrict__ bp,
    float* __restrict__ a, float* __restrict__ b, float* __restrict__ ptab) {
  const int e = threadIdx.x;  // 0..127
  if (blockIdx.x < NN) {
    const int i = blockIdx.x;
    __shared__ float row[INF];
    if (e < INF) row[e] = tf[i * INF + e];
    __syncthreads();
    float sa = ba[e];
    float sb = bb[e];
#pragma unroll
    for (int k = 0; k < INF; ++k) {
      float r = row[k];
      sa = fmaf(r, Wa[e * INF + k], sa);
      sb = fmaf(r, Wb[e * INF + k], sb);
    }
    a[i * EE + e] = sa;
    b[i * EE + e] = sb;
  } else {
    const int d = blockIdx.x - NN;  // 0..64
    ptab[d * EE + e] = Wp[e * NB + d] + bp[e];
  }
}

// Kernel 2: out[i][j][e] = a[i][e] + b[j][e] + p_lds[clip(ri_i-ri_j)][e]
// One block per row i. ptab staged in LDS (takes p-reads OFF the TCP port);
// b read from global (L2), output via nontemporal stores.
__global__ __launch_bounds__(512) void fill_kernel(
    const float* __restrict__ a, const float* __restrict__ b,
    const float* __restrict__ ptab, const int* __restrict__ ri,
    float* __restrict__ out) {
  __shared__ alignas(16) float p_lds[NB * EE];  // 32.5 KB
  __shared__ int sri[NN];                        // 4 KB

  const int tid = threadIdx.x;
  for (int t = tid; t < NN; t += 512) sri[t] = ri[t];
  {
    const f32x4* __restrict__ pg = reinterpret_cast<const f32x4*>(ptab);
    f32x4* pl = reinterpret_cast<f32x4*>(p_lds);
    for (int t = tid; t < NB * EE / 4; t += 512) pl[t] = pg[t];
  }
  __syncthreads();

  const int i  = blockIdx.x;
  const int e4 = tid & 31;   // f32x4 index within E
  const int jg = tid >> 5;   // 0..15

  const f32x4* __restrict__ b4 = reinterpret_cast<const f32x4*>(b);
  const f32x4* __restrict__ p4 = reinterpret_cast<const f32x4*>(p_lds);

  const f32x4 av = reinterpret_cast<const f32x4*>(a + i * EE)[e4];
  const int rii = sri[i];
  f32x4* outrow = reinterpret_cast<f32x4*>(out + (size_t)i * NN * EE);

  auto bin = [&](int j) {
    int d = rii - sri[j];
    d = (d < -BINSV) ? -BINSV : (d > BINSV ? BINSV : d);
    return d + BINSV;
  };

  // 1-deep pipeline on the global b-load; p comes from LDS inline.
  int j = jg;
  f32x4 bv = b4[j * 32 + e4];

  for (int jn = jg + 16; jn < NN; jn += 16) {
    f32x4 bvn = b4[jn * 32 + e4];
    const f32x4 o = av + bv + p4[bin(j) * 32 + e4];
    __builtin_nontemporal_store(o, outrow + j * 32 + e4);
    j = jn; bv = bvn;
  }
  const f32x4 o = av + bv + p4[bin(j) * 32 + e4];
  __builtin_nontemporal_store(o, outrow + j * 32 + e4);
}

extern "C" void kernel_launch(void* const* d_in, const int* in_sizes, int n_in,
                              void* d_out, int out_size, void* d_ws, size_t ws_size,
                              hipStream_t stream) {
  const float* tf = (const float*)d_in[0];
  const int*   ri = (const int*)d_in[1];
  const float* Wa = (const float*)d_in[2];
  const float* ba = (const float*)d_in[3];
  const float* Wb = (const float*)d_in[4];
  const float* bb = (const float*)d_in[5];
  const float* Wp = (const float*)d_in[6];
  const float* bp = (const float*)d_in[7];
  float* out = (float*)d_out;

  float* ws   = (float*)d_ws;
  float* a    = ws;                 // N*E floats
  float* b    = ws + NN * EE;       // N*E floats
  float* ptab = ws + 2 * NN * EE;   // 65*E floats

  prep_kernel<<<NN + NB, 128, 0, stream>>>(tf, Wa, ba, Wb, bb, Wp, bp, a, b, ptab);
  fill_kernel<<<NN, 512, 0, stream>>>(a, b, ptab, ri, out);
}